// Round 2
// baseline (15824.345 us; speedup 1.0000x reference)
//
#include <hip/hip_runtime.h>
#include <hip/hip_bf16.h>

typedef __hip_bfloat16 bf16;

// Problem constants
#define BATCH 8
#define NH 8
#define NTOK 3137         // H*W+1
#define HD 96             // head dim
#define HH 56
#define WW 56
#define KH 28
#define KW 28
#define NKEY 785          // KH*KW+1
#define DIMC 768
#define DIM3 2304
#define MROWS (BATCH * NTOK)   // 25096

__device__ __forceinline__ void cvt2(uint32_t u, float& a, float& b) {
  a = __uint_as_float(u << 16);
  b = __uint_as_float(u & 0xFFFF0000u);
}
__device__ __forceinline__ float b2f(bf16 x) { return __bfloat162float(x); }
__device__ __forceinline__ bf16 f2b(float x) { return __float2bfloat16(x); }

// ---------------- Kernel 1: QKV projection GEMM ----------------
// X: [25096, 768] fp32; W: [768, 2304] fp32; bias[2304] fp32
// Writes rawQ/rawK/rawV each [B][NH][NTOK][HD] in bf16
#define BM 64
#define BN 64
#define BK 16

__global__ __launch_bounds__(256) void k_qkv(
    const float* __restrict__ X, const float* __restrict__ W,
    const float* __restrict__ bias,
    bf16* __restrict__ Q, bf16* __restrict__ K, bf16* __restrict__ V) {
  __shared__ float As[BK][BM + 1];
  __shared__ float Bs[BK][BN + 1];
  const int bn = blockIdx.x;   // 0..35
  const int bm = blockIdx.y;   // 0..392
  const int tid = threadIdx.x;
  const int tx = tid % 16;     // N direction
  const int ty = tid / 16;     // M direction
  const int row0 = bm * BM;
  const int col0 = bn * BN;

  float acc[4][4] = {};

  for (int k0 = 0; k0 < DIMC; k0 += BK) {
#pragma unroll
    for (int i = 0; i < 4; i++) {
      int e = tid + i * 256;         // 0..1023
      int m = e / BK, kk = e % BK;
      int mm = row0 + m; if (mm >= MROWS) mm = MROWS - 1;
      As[kk][m] = X[(size_t)mm * DIMC + k0 + kk];
    }
#pragma unroll
    for (int i = 0; i < 4; i++) {
      int e = tid + i * 256;
      int kk = e / BN, n = e % BN;
      Bs[kk][n] = W[(size_t)(k0 + kk) * DIM3 + col0 + n];
    }
    __syncthreads();
#pragma unroll
    for (int kk = 0; kk < BK; kk++) {
      float a[4], b4[4];
#pragma unroll
      for (int i = 0; i < 4; i++) a[i] = As[kk][ty * 4 + i];
#pragma unroll
      for (int j = 0; j < 4; j++) b4[j] = Bs[kk][tx * 4 + j];
#pragma unroll
      for (int i = 0; i < 4; i++)
#pragma unroll
        for (int j = 0; j < 4; j++) acc[i][j] += a[i] * b4[j];
    }
    __syncthreads();
  }

#pragma unroll
  for (int i = 0; i < 4; i++) {
#pragma unroll
    for (int j = 0; j < 4; j++) {
      int m = row0 + ty * 4 + i;
      if (m >= MROWS) continue;
      int col = col0 + tx * 4 + j;
      float val = acc[i][j] + bias[col];
      int s = col / DIMC;         // 0,1,2 -> q,k,v
      int r = col % DIMC;
      int h = r / HD;
      int c = r % HD;
      int b = m / NTOK;
      int n = m % NTOK;
      bf16* dst = (s == 0) ? Q : (s == 1) ? K : V;
      dst[(((size_t)b * NH + h) * NTOK + n) * HD + c] = f2b(val);
    }
  }
}

// ---------------- Kernel 2: depthwise 3x3 pool + LayerNorm ----------------
// One 64-thread block per output token. raw: [bh][NTOK][HD] bf16 -> out bf16
template <int STRIDE, int OH, int OW>
__global__ __launch_bounds__(64) void k_pool(
    const bf16* __restrict__ raw, const float* __restrict__ wgt,
    const float* __restrict__ gam, const float* __restrict__ bet,
    bf16* __restrict__ out) {
  const int ntok = OH * OW + 1;
  const int t = blockIdx.x % ntok;
  const int bh = blockIdx.x / ntok;
  const int lane = threadIdx.x;
  const bf16* src = raw + (size_t)bh * NTOK * HD;

  float v0 = 0.f, v1 = 0.f;
  if (t == 0) {
    v0 = b2f(src[lane]);
    if (lane < 32) v1 = b2f(src[64 + lane]);
  } else {
    int oy = (t - 1) / OW, ox = (t - 1) % OW;
#pragma unroll
    for (int dy = 0; dy < 3; dy++) {
      int iy = oy * STRIDE + dy - 1;
      if (iy < 0 || iy >= HH) continue;
#pragma unroll
      for (int dx = 0; dx < 3; dx++) {
        int ix = ox * STRIDE + dx - 1;
        if (ix < 0 || ix >= WW) continue;
        const bf16* p = src + (size_t)(1 + iy * WW + ix) * HD;
        const float* wp = wgt + (dy * 3 + dx) * HD;
        v0 += b2f(p[lane]) * wp[lane];
        if (lane < 32) v1 += b2f(p[64 + lane]) * wp[64 + lane];
      }
    }
  }
  float s = v0 + ((lane < 32) ? v1 : 0.f);
  float s2 = v0 * v0 + ((lane < 32) ? v1 * v1 : 0.f);
#pragma unroll
  for (int o = 32; o > 0; o >>= 1) {
    s += __shfl_xor(s, o);
    s2 += __shfl_xor(s2, o);
  }
  float mean = s * (1.f / 96.f);
  float var = s2 * (1.f / 96.f) - mean * mean;
  float rstd = rsqrtf(var + 1e-5f);

  bf16* dst = out + ((size_t)bh * ntok + t) * HD;
  dst[lane] = f2b((v0 - mean) * rstd * gam[lane] + bet[lane]);
  if (lane < 32) dst[64 + lane] = f2b((v1 - mean) * rstd * gam[64 + lane] + bet[64 + lane]);
}

// ---------------- Kernel 3: fused attention ----------------
// Qp: [bh][NTOK][HD] bf16; Kp,Vp: [bh][NKEY][HD] bf16; relH/relW: [111][HD] fp32
// out: [b][n][h*HD + c] fp32 (fused transpose + residual)
__global__ __launch_bounds__(256) void k_attn(
    const bf16* __restrict__ Qp, const bf16* __restrict__ Kp,
    const bf16* __restrict__ Vp, const float* __restrict__ relHt,
    const float* __restrict__ relWt, float* __restrict__ out) {
  __shared__ __align__(16) float qrow[4][HD];
  __shared__ float relh[4][KH];
  __shared__ float relw[4][KW];
  __shared__ float probs[4][NKEY];

  const int qt = blockIdx.x % 785;   // query tile (4 queries)
  const int bh = blockIdx.x / 785;
  const int wid = threadIdx.x / 64;
  const int lane = threadIdx.x % 64;
  const int qi = qt * 4 + wid;
  const bool act = qi < NTOK;
  const float scale = 0.10206207261596575f;  // 96^-0.5

  if (act) {
    const bf16* qptr = Qp + ((size_t)bh * NTOK + qi) * HD;
    qrow[wid][lane] = b2f(qptr[lane]);
    if (lane < 32) qrow[wid][64 + lane] = b2f(qptr[64 + lane]);
  }
  __syncthreads();

  // rel-pos dot products
  if (act && qi > 0) {
    int qy = (qi - 1) / WW;
    int qx = (qi - 1) % WW;
    if (lane < KH) {
      const float* rp = relHt + (size_t)(qy - 2 * lane + 54) * HD;
      float d = 0.f;
#pragma unroll
      for (int c = 0; c < HD; c++) d += qrow[wid][c] * rp[c];
      relh[wid][lane] = d;
    } else if (lane >= 32 && lane < 32 + KW) {
      int kx = lane - 32;
      const float* rp = relWt + (size_t)(qx - 2 * kx + 54) * HD;
      float d = 0.f;
#pragma unroll
      for (int c = 0; c < HD; c++) d += qrow[wid][c] * rp[c];
      relw[wid][kx] = d;
    }
  }
  __syncthreads();

  // logits
  float lmax = -1e30f;
  if (act) {
    for (int ki = lane; ki < NKEY; ki += 64) {
      const uint4* kp4 = reinterpret_cast<const uint4*>(Kp + ((size_t)bh * NKEY + ki) * HD);
      float d = 0.f;
#pragma unroll
      for (int c4 = 0; c4 < HD / 8; c4++) {   // 12 x uint4 = 96 bf16
        uint4 u = kp4[c4];
        float f0, f1, f2, f3, f4, f5, f6, f7;
        cvt2(u.x, f0, f1); cvt2(u.y, f2, f3);
        cvt2(u.z, f4, f5); cvt2(u.w, f6, f7);
        const float* q = &qrow[wid][c4 * 8];
        d += q[0] * f0 + q[1] * f1 + q[2] * f2 + q[3] * f3 +
             q[4] * f4 + q[5] * f5 + q[6] * f6 + q[7] * f7;
      }
      float lg = d * scale;
      if (qi > 0 && ki > 0) {
        int ky = (ki - 1) / KW;
        int kx = (ki - 1) % KW;
        lg += relh[wid][ky] + relw[wid][kx];
      }
      probs[wid][ki] = lg;
      lmax = fmaxf(lmax, lg);
    }
  }
#pragma unroll
  for (int o = 32; o > 0; o >>= 1) lmax = fmaxf(lmax, __shfl_xor(lmax, o));

  float lsum = 0.f;
  if (act) {
    for (int ki = lane; ki < NKEY; ki += 64) {
      float e = __expf(probs[wid][ki] - lmax);
      probs[wid][ki] = e;
      lsum += e;
    }
  }
#pragma unroll
  for (int o = 32; o > 0; o >>= 1) lsum += __shfl_xor(lsum, o);
  float inv = 1.f / lsum;

  // PV + residual + transposed store
  if (act) {
    const bf16* vb = Vp + (size_t)bh * NKEY * HD;
    float o0 = 0.f, o1 = 0.f;
    for (int ki = 0; ki < NKEY; ki++) {
      float p = probs[wid][ki];
      o0 += p * b2f(vb[(size_t)ki * HD + lane]);
      if (lane < 32) o1 += p * b2f(vb[(size_t)ki * HD + 64 + lane]);
    }
    o0 *= inv;
    o1 *= inv;
    int b = bh / NH, h = bh % NH;
    float* op = out + ((size_t)b * NTOK + qi) * (NH * HD) + h * HD;
    op[lane] = o0 + qrow[wid][lane];
    if (lane < 32) op[64 + lane] = o1 + qrow[wid][64 + lane];
  }
}

// ---------------- launch ----------------
extern "C" void kernel_launch(void* const* d_in, const int* in_sizes, int n_in,
                              void* d_out, int out_size, void* d_ws, size_t ws_size,
                              hipStream_t stream) {
  const float* x = (const float*)d_in[0];
  const float* qkv_w = (const float*)d_in[1];
  const float* qkv_b = (const float*)d_in[2];
  const float* pqw = (const float*)d_in[3];
  const float* pkw = (const float*)d_in[4];
  const float* pvw = (const float*)d_in[5];
  const float* nqg = (const float*)d_in[6];
  const float* nqb = (const float*)d_in[7];
  const float* nkg = (const float*)d_in[8];
  const float* nkb = (const float*)d_in[9];
  const float* nvg = (const float*)d_in[10];
  const float* nvb = (const float*)d_in[11];
  const float* relH = (const float*)d_in[12];
  const float* relW = (const float*)d_in[13];

  const size_t SZQ = (size_t)BATCH * NH * NTOK * HD;   // 19,267,584 elems
  const size_t SZK = (size_t)BATCH * NH * NKEY * HD;   //  4,823,040 elems

  // Workspace layout (bf16), peak 96.3 MB:
  //   rawQ  [0,        SZQ)
  //   rawK  [SZQ,    2*SZQ)   -> reused as poolQ after poolK completes
  //   poolK [2*SZQ,  2*SZQ+SZK)
  //   poolV [2*SZQ+SZK, 2*SZQ+2*SZK)
  // rawV lives in d_out (77 MB fp32 >= 38.5 MB bf16), dead before attn writes.
  bf16* ws = (bf16*)d_ws;
  bf16* rawQ = ws;
  bf16* rawK = ws + SZQ;
  bf16* rawV = (bf16*)d_out;
  bf16* poolK = ws + 2 * SZQ;
  bf16* poolV = poolK + SZK;
  bf16* poolQ = rawK;          // aliases rawK (dead after poolK kernel)
  float* out = (float*)d_out;

  dim3 g1(DIM3 / BN, (MROWS + BM - 1) / BM);  // (36, 393)
  k_qkv<<<g1, 256, 0, stream>>>(x, qkv_w, qkv_b, rawQ, rawK, rawV);

  // Order matters for aliasing: consume rawK and rawV before overwriting.
  k_pool<2, 28, 28><<<BATCH * NH * NKEY, 64, 0, stream>>>(rawK, pkw, nkg, nkb, poolK);
  k_pool<2, 28, 28><<<BATCH * NH * NKEY, 64, 0, stream>>>(rawV, pvw, nvg, nvb, poolV);
  k_pool<1, 56, 56><<<BATCH * NH * NTOK, 64, 0, stream>>>(rawQ, pqw, nqg, nqb, poolQ);

  k_attn<<<BATCH * NH * 785, 256, 0, stream>>>(poolQ, poolK, poolV, relH, relW, out);
}

// Round 4
// 2500.366 us; speedup vs baseline: 6.3288x; 6.3288x over previous
//
#include <hip/hip_runtime.h>
#include <hip/hip_bf16.h>

typedef __hip_bfloat16 bf16;
typedef __attribute__((ext_vector_type(8))) short s16x8;
typedef __attribute__((ext_vector_type(4))) short s16x4;
typedef __attribute__((ext_vector_type(4))) float f32x4;

// Problem constants
#define BATCH 8
#define NH 8
#define NTOK 3137         // H*W+1
#define HD 96             // head dim
#define HH 56
#define WW 56
#define NKEY 785          // 28*28+1
#define DIMC 768
#define DIM3 2304
#define MROWS (BATCH * NTOK)   // 25096

__device__ __forceinline__ float b2f(bf16 x) { return __bfloat162float(x); }
__device__ __forceinline__ bf16 f2b(float x) { return __float2bfloat16(x); }
__device__ __forceinline__ float s2f(short s) {
  return __uint_as_float(((uint32_t)(uint16_t)s) << 16);
}
__device__ __forceinline__ short f2bs(float x) {
  bf16 h = __float2bfloat16(x);
  short s; __builtin_memcpy(&s, &h, 2); return s;
}

// ---------------- Kernel 1: QKV projection GEMM (fp32, unchanged) ----------------
#define BM 64
#define BN 64
#define BK 16

__global__ __launch_bounds__(256) void k_qkv(
    const float* __restrict__ X, const float* __restrict__ W,
    const float* __restrict__ bias,
    bf16* __restrict__ Q, bf16* __restrict__ K, bf16* __restrict__ V) {
  __shared__ float As[BK][BM + 1];
  __shared__ float Bs[BK][BN + 1];
  const int bn = blockIdx.x;
  const int bm = blockIdx.y;
  const int tid = threadIdx.x;
  const int tx = tid % 16;
  const int ty = tid / 16;
  const int row0 = bm * BM;
  const int col0 = bn * BN;

  float acc[4][4] = {};

  for (int k0 = 0; k0 < DIMC; k0 += BK) {
#pragma unroll
    for (int i = 0; i < 4; i++) {
      int e = tid + i * 256;
      int m = e / BK, kk = e % BK;
      int mm = row0 + m; if (mm >= MROWS) mm = MROWS - 1;
      As[kk][m] = X[(size_t)mm * DIMC + k0 + kk];
    }
#pragma unroll
    for (int i = 0; i < 4; i++) {
      int e = tid + i * 256;
      int kk = e / BN, n = e % BN;
      Bs[kk][n] = W[(size_t)(k0 + kk) * DIM3 + col0 + n];
    }
    __syncthreads();
#pragma unroll
    for (int kk = 0; kk < BK; kk++) {
      float a[4], b4[4];
#pragma unroll
      for (int i = 0; i < 4; i++) a[i] = As[kk][ty * 4 + i];
#pragma unroll
      for (int j = 0; j < 4; j++) b4[j] = Bs[kk][tx * 4 + j];
#pragma unroll
      for (int i = 0; i < 4; i++)
#pragma unroll
        for (int j = 0; j < 4; j++) acc[i][j] += a[i] * b4[j];
    }
    __syncthreads();
  }

#pragma unroll
  for (int i = 0; i < 4; i++) {
#pragma unroll
    for (int j = 0; j < 4; j++) {
      int m = row0 + ty * 4 + i;
      if (m >= MROWS) continue;
      int col = col0 + tx * 4 + j;
      float val = acc[i][j] + bias[col];
      int s = col / DIMC;
      int r = col % DIMC;
      int h = r / HD;
      int c = r % HD;
      int b = m / NTOK;
      int n = m % NTOK;
      bf16* dst = (s == 0) ? Q : (s == 1) ? K : V;
      dst[(((size_t)b * NH + h) * NTOK + n) * HD + c] = f2b(val);
    }
  }
}

// ---------------- Kernel 2: depthwise 3x3 pool + LayerNorm (unchanged) ----------------
template <int STRIDE, int OH, int OW>
__global__ __launch_bounds__(64) void k_pool(
    const bf16* __restrict__ raw, const float* __restrict__ wgt,
    const float* __restrict__ gam, const float* __restrict__ bet,
    bf16* __restrict__ out) {
  const int ntok = OH * OW + 1;
  const int t = blockIdx.x % ntok;
  const int bh = blockIdx.x / ntok;
  const int lane = threadIdx.x;
  const bf16* src = raw + (size_t)bh * NTOK * HD;

  float v0 = 0.f, v1 = 0.f;
  if (t == 0) {
    v0 = b2f(src[lane]);
    if (lane < 32) v1 = b2f(src[64 + lane]);
  } else {
    int oy = (t - 1) / OW, ox = (t - 1) % OW;
#pragma unroll
    for (int dy = 0; dy < 3; dy++) {
      int iy = oy * STRIDE + dy - 1;
      if (iy < 0 || iy >= HH) continue;
#pragma unroll
      for (int dx = 0; dx < 3; dx++) {
        int ix = ox * STRIDE + dx - 1;
        if (ix < 0 || ix >= WW) continue;
        const bf16* p = src + (size_t)(1 + iy * WW + ix) * HD;
        const float* wp = wgt + (dy * 3 + dx) * HD;
        v0 += b2f(p[lane]) * wp[lane];
        if (lane < 32) v1 += b2f(p[64 + lane]) * wp[64 + lane];
      }
    }
  }
  float s = v0 + ((lane < 32) ? v1 : 0.f);
  float s2 = v0 * v0 + ((lane < 32) ? v1 * v1 : 0.f);
#pragma unroll
  for (int o = 32; o > 0; o >>= 1) {
    s += __shfl_xor(s, o);
    s2 += __shfl_xor(s2, o);
  }
  float mean = s * (1.f / 96.f);
  float var = s2 * (1.f / 96.f) - mean * mean;
  float rstd = rsqrtf(var + 1e-5f);

  bf16* dst = out + ((size_t)bh * ntok + t) * HD;
  dst[lane] = f2b((v0 - mean) * rstd * gam[lane] + bet[lane]);
  if (lane < 32) dst[64 + lane] = f2b((v1 - mean) * rstd * gam[64 + lane] + bet[64 + lane]);
}

// ---------------- Kernel 3: MFMA flash attention ----------------
// Block = 64 queries (4 waves x 16) for one bh; KV tiles of 32, double-buffered.
// mfma_f32_16x16x32_bf16: A lane: row=l&15, k=8*(l>>4)+j ; B lane: col=l&15, same k
// C/D: col=lane&15, row=(lane>>4)*4+reg  (m89/m91-verified)
__global__ __launch_bounds__(256, 3) void k_attn(
    const bf16* __restrict__ Qp, const bf16* __restrict__ Kp,
    const bf16* __restrict__ Vp, const float* __restrict__ relHt,
    const float* __restrict__ relWt, float* __restrict__ out) {
  // K tile: [32 rows][128 elem rows (256B), chunks XOR-swizzled by k&7]
  __shared__ __align__(16) short Ks[2][32 * 128];
  // V tile: 6 cblks of [32 k][16 c] row-major (tr-read layout)
  __shared__ __align__(16) short Vs[2][6 * 512];
  __shared__ __align__(16) short Qs[64 * 96];
  __shared__ short RH[64 * 28];
  __shared__ short RW[64 * 28];
  // P per wave: [16 q][32 k], chunks XOR-swizzled by (q>>1)&3
  __shared__ __align__(16) short Ps[4][512];

  const int bh = blockIdx.x / 50;
  const int qt = blockIdx.x % 50;
  const int qbase = qt * 64;
  const int tid = threadIdx.x;
  const int wid = tid >> 6;
  const int lane = tid & 63;
  const int g = lane >> 4;
  const int kl = lane & 15;
  const int bb = bh >> 3, hh = bh & 7;
  const float scale = 0.10206207261596575f;

  const bf16* Qbh = Qp + (size_t)bh * NTOK * HD;
  const bf16* Kbh = Kp + (size_t)bh * NKEY * HD;
  const bf16* Vbh = Vp + (size_t)bh * NKEY * HD;

  // ---- stage Q tile (64 x 96) ----
  for (int idx = tid; idx < 768; idx += 256) {
    int ql = idx / 12, ch = idx % 12;
    int qg = qbase + ql; if (qg > NTOK - 1) qg = NTOK - 1;
    uint4 u = *(const uint4*)(Qbh + (size_t)qg * HD + ch * 8);
    *(uint4*)&Qs[ql * 96 + ch * 8] = u;
  }
  __syncthreads();

  // ---- Q fragments (A operand) ----
  s16x8 qf[3];
  {
    const short* qrow = &Qs[(wid * 16 + kl) * 96];
#pragma unroll
    for (int f = 0; f < 3; f++) qf[f] = *(const s16x8*)(qrow + f * 32 + g * 8);
  }

  // ---- rel-pos tables: RH/RW[64][28] ----
  for (int idx = tid; idx < 1792; idx += 256) {
    int ql = idx / 28, j = idx % 28;
    int qg = qbase + ql; if (qg > NTOK - 1) qg = NTOK - 1;
    int qy, qx;
    if (qg < 1) { qy = 0; qx = 0; } else { qy = (qg - 1) / 56; qx = (qg - 1) % 56; }
    int ih = qy - 2 * j + 54; ih = ih < 0 ? 0 : (ih > 110 ? 110 : ih);
    int iw = qx - 2 * j + 54; iw = iw < 0 ? 0 : (iw > 110 ? 110 : iw);
    const float* ph = relHt + (size_t)ih * HD;
    const float* pw = relWt + (size_t)iw * HD;
    float dh = 0.f, dw = 0.f;
    for (int c = 0; c < HD; c++) {
      float qv = s2f(Qs[ql * 96 + c]);
      dh += qv * ph[c]; dw += qv * pw[c];
    }
    RH[ql * 28 + j] = f2bs(dh);
    RW[ql * 28 + j] = f2bs(dw);
  }

  // ---- KV staging helper ----
  auto stage_kv = [&](int t, int buf) {
    for (int idx = tid; idx < 384; idx += 256) {
      int kk = idx / 12, ch = idx % 12;
      int ks = t * 32 + kk; if (ks > 784) ks = 784;
      uint4 u = *(const uint4*)(Kbh + (size_t)ks * HD + ch * 8);
      *(uint4*)&Ks[buf][kk * 128 + ((ch ^ (kk & 7)) << 3)] = u;
      uint4 v = *(const uint4*)(Vbh + (size_t)ks * HD + ch * 8);
      *(uint4*)&Vs[buf][(ch >> 1) * 512 + kk * 16 + ((ch & 1) << 3)] = v;
    }
  };

  stage_kv(0, 0);
  __syncthreads();

  f32x4 o[6];
#pragma unroll
  for (int cb = 0; cb < 6; cb++) o[cb] = (f32x4){0.f, 0.f, 0.f, 0.f};
  float mrow[4] = {-1e30f, -1e30f, -1e30f, -1e30f};
  float lrow[4] = {0.f, 0.f, 0.f, 0.f};

  for (int t = 0; t < 25; t++) {
    const int buf = t & 1;
    if (t < 24) stage_kv(t + 1, buf ^ 1);

    // ---- QK^T: S[16q][32k] in two 16-key fragments ----
    f32x4 s0 = (f32x4){0.f, 0.f, 0.f, 0.f};
    f32x4 s1 = (f32x4){0.f, 0.f, 0.f, 0.f};
#pragma unroll
    for (int f = 0; f < 3; f++) {
      int ch = f * 4 + g;
      int r0 = kl, r1 = 16 + kl;
      s16x8 kf0 = *(const s16x8*)&Ks[buf][r0 * 128 + ((ch ^ (r0 & 7)) << 3)];
      s16x8 kf1 = *(const s16x8*)&Ks[buf][r1 * 128 + ((ch ^ (r1 & 7)) << 3)];
      s0 = __builtin_amdgcn_mfma_f32_16x16x32_bf16(qf[f], kf0, s0, 0, 0, 0);
      s1 = __builtin_amdgcn_mfma_f32_16x16x32_bf16(qf[f], kf1, s1, 0, 0, 0);
    }

    // ---- scale + rel-pos + mask ----
    const int k0g = t * 32 + kl;       // always <= 783 (valid)
    const int k1g = k0g + 16;          // may exceed 784
    int ky0 = (k0g - 1) / 28, kx0 = (k0g - 1) % 28;
    if (kx0 < 0) kx0 = 0;
    int ky1 = (k1g - 1) / 28, kx1 = (k1g - 1) % 28;
    if (ky1 > 27) ky1 = 27;
    float lg0[4], lg1[4];
#pragma unroll
    for (int r = 0; r < 4; r++) {
      int ql = wid * 16 + g * 4 + r;
      int qg = qbase + ql;
      float rel0 = (qg > 0 && k0g > 0) ? s2f(RH[ql * 28 + ky0]) + s2f(RW[ql * 28 + kx0]) : 0.f;
      float rel1 = (qg > 0) ? s2f(RH[ql * 28 + ky1]) + s2f(RW[ql * 28 + kx1]) : 0.f;
      lg0[r] = s0[r] * scale + rel0;
      lg1[r] = (k1g < NKEY) ? (s1[r] * scale + rel1) : -1e30f;
    }

    // ---- online softmax (rows live in 16-lane groups) ----
    float tm[4], al[4], p0[4], p1[4], rs[4];
#pragma unroll
    for (int r = 0; r < 4; r++) tm[r] = fmaxf(lg0[r], lg1[r]);
#pragma unroll
    for (int off = 1; off < 16; off <<= 1)
#pragma unroll
      for (int r = 0; r < 4; r++) tm[r] = fmaxf(tm[r], __shfl_xor(tm[r], off));
#pragma unroll
    for (int r = 0; r < 4; r++) {
      float mn = fmaxf(mrow[r], tm[r]);
      al[r] = __expf(mrow[r] - mn);
      p0[r] = __expf(lg0[r] - mn);
      p1[r] = __expf(lg1[r] - mn);
      mrow[r] = mn;
      rs[r] = p0[r] + p1[r];
    }
#pragma unroll
    for (int off = 1; off < 16; off <<= 1)
#pragma unroll
      for (int r = 0; r < 4; r++) rs[r] += __shfl_xor(rs[r], off);
#pragma unroll
    for (int r = 0; r < 4; r++) lrow[r] = lrow[r] * al[r] + rs[r];
#pragma unroll
    for (int cb = 0; cb < 6; cb++)
#pragma unroll
      for (int r = 0; r < 4; r++) o[cb][r] *= al[r];

    // ---- P -> LDS (swizzled [16][32]) ----
    short* pw = &Ps[wid][0];
#pragma unroll
    for (int r = 0; r < 4; r++) {
      int q = g * 4 + r;
      int sw = (q >> 1) & 3;
      pw[q * 32 + (((kl >> 3) ^ sw) << 3) + (kl & 7)] = f2bs(p0[r]);
      int k1 = 16 + kl;
      pw[q * 32 + (((k1 >> 3) ^ sw) << 3) + (kl & 7)] = f2bs(p1[r]);
    }
    s16x8 pa = *(const s16x8*)(pw + kl * 32 + ((g ^ ((kl >> 1) & 3)) << 3));

    // ---- PV via hardware-transpose reads of V ----
    // tr_b16 semantics: each lane fetches 8 CONTIGUOUS bytes; the crossbar
    // delivers column (l&15) of the group's 4x16 window. Per-lane addr must
    // be windowbase + (l&15)*8 bytes; window for group g = rows 8g..8g+3
    // of the [32][16] cblk = 128 B at g*256.  (kl*2 in R3 was the bug.)
    uint32_t vbase = (uint32_t)(size_t)&Vs[buf][0] + (uint32_t)(g * 256 + kl * 8);
    s16x4 tv[12];
#pragma unroll
    for (int cb = 0; cb < 6; cb++) {
      uint32_t va = vbase + cb * 1024;
      asm volatile("ds_read_b64_tr_b16 %0, %1" : "=v"(tv[2 * cb]) : "v"(va));
      asm volatile("ds_read_b64_tr_b16 %0, %1 offset:128" : "=v"(tv[2 * cb + 1]) : "v"(va));
    }
    asm volatile("s_waitcnt lgkmcnt(0)" ::: "memory");
    __builtin_amdgcn_sched_barrier(0);
#pragma unroll
    for (int cb = 0; cb < 6; cb++) {
      s16x8 vf = __builtin_shufflevector(tv[2 * cb], tv[2 * cb + 1], 0, 1, 2, 3, 4, 5, 6, 7);
      o[cb] = __builtin_amdgcn_mfma_f32_16x16x32_bf16(pa, vf, o[cb], 0, 0, 0);
    }
    __syncthreads();
  }

  // ---- epilogue: normalize + residual + transposed store ----
  float inv[4];
#pragma unroll
  for (int r = 0; r < 4; r++) inv[r] = 1.f / lrow[r];
#pragma unroll
  for (int cb = 0; cb < 6; cb++) {
#pragma unroll
    for (int r = 0; r < 4; r++) {
      int ql = wid * 16 + g * 4 + r;
      int qg = qbase + ql;
      if (qg < NTOK) {
        int c = cb * 16 + kl;
        float val = o[cb][r] * inv[r] + s2f(Qs[ql * 96 + c]);
        out[((size_t)bb * NTOK + qg) * 768 + hh * 96 + c] = val;
      }
    }
  }
}

// ---------------- launch ----------------
extern "C" void kernel_launch(void* const* d_in, const int* in_sizes, int n_in,
                              void* d_out, int out_size, void* d_ws, size_t ws_size,
                              hipStream_t stream) {
  const float* x = (const float*)d_in[0];
  const float* qkv_w = (const float*)d_in[1];
  const float* qkv_b = (const float*)d_in[2];
  const float* pqw = (const float*)d_in[3];
  const float* pkw = (const float*)d_in[4];
  const float* pvw = (const float*)d_in[5];
  const float* nqg = (const float*)d_in[6];
  const float* nqb = (const float*)d_in[7];
  const float* nkg = (const float*)d_in[8];
  const float* nkb = (const float*)d_in[9];
  const float* nvg = (const float*)d_in[10];
  const float* nvb = (const float*)d_in[11];
  const float* relH = (const float*)d_in[12];
  const float* relW = (const float*)d_in[13];

  const size_t SZQ = (size_t)BATCH * NH * NTOK * HD;
  const size_t SZK = (size_t)BATCH * NH * NKEY * HD;

  bf16* ws = (bf16*)d_ws;
  bf16* rawQ = ws;
  bf16* rawK = ws + SZQ;
  bf16* rawV = (bf16*)d_out;
  bf16* poolK = ws + 2 * SZQ;
  bf16* poolV = poolK + SZK;
  bf16* poolQ = rawK;          // aliases rawK (dead after poolK kernel)
  float* out = (float*)d_out;

  dim3 g1(DIM3 / BN, (MROWS + BM - 1) / BM);
  k_qkv<<<g1, 256, 0, stream>>>(x, qkv_w, qkv_b, rawQ, rawK, rawV);

  k_pool<2, 28, 28><<<BATCH * NH * NKEY, 64, 0, stream>>>(rawK, pkw, nkg, nkb, poolK);
  k_pool<2, 28, 28><<<BATCH * NH * NKEY, 64, 0, stream>>>(rawV, pvw, nvg, nvb, poolV);
  k_pool<1, 56, 56><<<BATCH * NH * NTOK, 64, 0, stream>>>(rawQ, pqw, nqg, nqb, poolQ);

  k_attn<<<64 * 50, 256, 0, stream>>>(poolQ, poolK, poolV, relH, relW, out);
}

// Round 5
// 1018.520 us; speedup vs baseline: 15.5366x; 2.4549x over previous
//
#include <hip/hip_runtime.h>
#include <hip/hip_bf16.h>

typedef __hip_bfloat16 bf16;
typedef __attribute__((ext_vector_type(8))) short s16x8;
typedef __attribute__((ext_vector_type(4))) short s16x4;
typedef __attribute__((ext_vector_type(4))) float f32x4;

// Problem constants
#define BATCH 8
#define NH 8
#define NTOK 3137         // H*W+1
#define HD 96             // head dim
#define HH 56
#define WW 56
#define NKEY 785          // 28*28+1
#define DIMC 768
#define DIM3 2304
#define MROWS (BATCH * NTOK)   // 25096

__device__ __forceinline__ float b2f(bf16 x) { return __bfloat162float(x); }
__device__ __forceinline__ bf16 f2b(float x) { return __float2bfloat16(x); }
__device__ __forceinline__ float s2f(short s) {
  return __uint_as_float(((uint32_t)(uint16_t)s) << 16);
}
__device__ __forceinline__ short f2bs(float x) {
  bf16 h = __float2bfloat16(x);
  short s; __builtin_memcpy(&s, &h, 2); return s;
}
__device__ __forceinline__ void gload_lds16(const void* g, void* l) {
  __builtin_amdgcn_global_load_lds(
      (const __attribute__((address_space(1))) void*)g,
      (__attribute__((address_space(3))) void*)l, 16, 0, 0);
}

// ---------------- Kernel 0a: X fp32 -> bf16 ----------------
__global__ __launch_bounds__(256) void k_cvtX(const float* __restrict__ X,
                                              bf16* __restrict__ Xb, int n4) {
  for (int i = blockIdx.x * blockDim.x + threadIdx.x; i < n4;
       i += gridDim.x * blockDim.x) {
    float4 v = reinterpret_cast<const float4*>(X)[i];
    ushort4 o;
    o.x = (unsigned short)f2bs(v.x); o.y = (unsigned short)f2bs(v.y);
    o.z = (unsigned short)f2bs(v.z); o.w = (unsigned short)f2bs(v.w);
    reinterpret_cast<ushort4*>(Xb)[i] = o;
  }
}

// ---------------- Kernel 0b: W [768][2304] fp32 -> W^T [2304][768] bf16 ----------------
__global__ __launch_bounds__(256) void k_cvtW(const float* __restrict__ W,
                                              bf16* __restrict__ WbT) {
  __shared__ float T[64][65];
  const int n0 = blockIdx.x * 64;   // 36
  const int k0 = blockIdx.y * 64;   // 12
  const int tid = threadIdx.x;
#pragma unroll
  for (int i = 0; i < 16; i++) {
    int e = tid + i * 256;
    int r = e >> 6, c = e & 63;          // r: k, c: n  (coalesced read)
    T[r][c] = W[(size_t)(k0 + r) * DIM3 + n0 + c];
  }
  __syncthreads();
#pragma unroll
  for (int i = 0; i < 16; i++) {
    int e = tid + i * 256;
    int r = e >> 6, c = e & 63;          // r: n, c: k  (coalesced write)
    WbT[(size_t)(n0 + r) * DIMC + k0 + c] = f2b(T[c][r]);
  }
}

// ---------------- Kernel 1: QKV projection, bf16 MFMA ----------------
// C = Xb[25096x768] * WbT^T ; tile 128x128, BK=32, 4 waves in 2x2 of 64x64.
// LDS layout [g][row][8] so each 16-lane group reads consecutive 16B slots.
__global__ __launch_bounds__(256) void k_qkv_mfma(
    const bf16* __restrict__ Xb, const bf16* __restrict__ WbT,
    const float* __restrict__ bias,
    bf16* __restrict__ Q, bf16* __restrict__ K, bf16* __restrict__ V) {
  __shared__ __align__(16) short As[4 * 128 * 8];   // 8 KB
  __shared__ __align__(16) short Bs[4 * 128 * 8];   // 8 KB
  const int tid = threadIdx.x;
  const int wid = tid >> 6, lane = tid & 63;
  const int g = lane >> 4, kl = lane & 15;
  const int wm = wid >> 1, wn = wid & 1;
  const int row0 = blockIdx.y * 128;
  const int col0 = blockIdx.x * 128;

  f32x4 acc[4][4] = {};

  for (int k0 = 0; k0 < DIMC; k0 += 32) {
#pragma unroll
    for (int r = 0; r < 2; r++) {
      int slot = r * 256 + wid * 64 + lane;       // 0..511
      int sg = slot >> 7, sm = slot & 127;
      int mm = row0 + sm; if (mm > MROWS - 1) mm = MROWS - 1;
      const bf16* gpA = Xb + (size_t)mm * DIMC + k0 + sg * 8;
      short* lpA = As + ((r * 256 + wid * 64) << 3);
      gload_lds16(gpA, lpA);
      const bf16* gpB = WbT + (size_t)(col0 + sm) * DIMC + k0 + sg * 8;
      short* lpB = Bs + ((r * 256 + wid * 64) << 3);
      gload_lds16(gpB, lpB);
    }
    __syncthreads();

    s16x8 af[4], bf[4];
#pragma unroll
    for (int i = 0; i < 4; i++)
      af[i] = *(const s16x8*)&As[((g << 7) + wm * 64 + i * 16 + kl) << 3];
#pragma unroll
    for (int j = 0; j < 4; j++)
      bf[j] = *(const s16x8*)&Bs[((g << 7) + wn * 64 + j * 16 + kl) << 3];
#pragma unroll
    for (int i = 0; i < 4; i++)
#pragma unroll
      for (int j = 0; j < 4; j++)
        acc[i][j] = __builtin_amdgcn_mfma_f32_16x16x32_bf16(af[i], bf[j], acc[i][j], 0, 0, 0);
    __syncthreads();
  }

  // epilogue: bias + scatter to Q/K/V [b][h][n][c] bf16
#pragma unroll
  for (int i = 0; i < 4; i++) {
    int mbase = row0 + wm * 64 + i * 16 + (lane >> 4) * 4;
#pragma unroll
    for (int j = 0; j < 4; j++) {
      int n = col0 + wn * 64 + j * 16 + kl;
      int s = n / DIMC, rr = n % DIMC;
      int h = rr / HD, c = rr % HD;
      bf16* dst = (s == 0) ? Q : (s == 1) ? K : V;
      float bv = bias[n];
#pragma unroll
      for (int r = 0; r < 4; r++) {
        int mm = mbase + r;
        if (mm >= MROWS) continue;
        int b = mm / NTOK, nt = mm % NTOK;
        dst[(((size_t)b * NH + h) * NTOK + nt) * HD + c] = f2b(acc[i][j][r] + bv);
      }
    }
  }
}

// ---------------- Kernel 2: depthwise 3x3 pool + LayerNorm (unchanged) ----------------
template <int STRIDE, int OH, int OW>
__global__ __launch_bounds__(64) void k_pool(
    const bf16* __restrict__ raw, const float* __restrict__ wgt,
    const float* __restrict__ gam, const float* __restrict__ bet,
    bf16* __restrict__ out) {
  const int ntok = OH * OW + 1;
  const int t = blockIdx.x % ntok;
  const int bh = blockIdx.x / ntok;
  const int lane = threadIdx.x;
  const bf16* src = raw + (size_t)bh * NTOK * HD;

  float v0 = 0.f, v1 = 0.f;
  if (t == 0) {
    v0 = b2f(src[lane]);
    if (lane < 32) v1 = b2f(src[64 + lane]);
  } else {
    int oy = (t - 1) / OW, ox = (t - 1) % OW;
#pragma unroll
    for (int dy = 0; dy < 3; dy++) {
      int iy = oy * STRIDE + dy - 1;
      if (iy < 0 || iy >= HH) continue;
#pragma unroll
      for (int dx = 0; dx < 3; dx++) {
        int ix = ox * STRIDE + dx - 1;
        if (ix < 0 || ix >= WW) continue;
        const bf16* p = src + (size_t)(1 + iy * WW + ix) * HD;
        const float* wp = wgt + (dy * 3 + dx) * HD;
        v0 += b2f(p[lane]) * wp[lane];
        if (lane < 32) v1 += b2f(p[64 + lane]) * wp[64 + lane];
      }
    }
  }
  float s = v0 + ((lane < 32) ? v1 : 0.f);
  float s2 = v0 * v0 + ((lane < 32) ? v1 * v1 : 0.f);
#pragma unroll
  for (int o = 32; o > 0; o >>= 1) {
    s += __shfl_xor(s, o);
    s2 += __shfl_xor(s2, o);
  }
  float mean = s * (1.f / 96.f);
  float var = s2 * (1.f / 96.f) - mean * mean;
  float rstd = rsqrtf(var + 1e-5f);

  bf16* dst = out + ((size_t)bh * ntok + t) * HD;
  dst[lane] = f2b((v0 - mean) * rstd * gam[lane] + bet[lane]);
  if (lane < 32) dst[64 + lane] = f2b((v1 - mean) * rstd * gam[64 + lane] + bet[64 + lane]);
}

// ---------------- Kernel 3: MFMA flash attention (unchanged from R4-pass) ----------------
__global__ __launch_bounds__(256, 3) void k_attn(
    const bf16* __restrict__ Qp, const bf16* __restrict__ Kp,
    const bf16* __restrict__ Vp, const float* __restrict__ relHt,
    const float* __restrict__ relWt, float* __restrict__ out) {
  __shared__ __align__(16) short Ks[2][32 * 128];
  __shared__ __align__(16) short Vs[2][6 * 512];
  __shared__ __align__(16) short Qs[64 * 96];
  __shared__ short RH[64 * 28];
  __shared__ short RW[64 * 28];
  __shared__ __align__(16) short Ps[4][512];

  const int bh = blockIdx.x / 50;
  const int qt = blockIdx.x % 50;
  const int qbase = qt * 64;
  const int tid = threadIdx.x;
  const int wid = tid >> 6;
  const int lane = tid & 63;
  const int g = lane >> 4;
  const int kl = lane & 15;
  const int bb = bh >> 3, hh = bh & 7;
  const float scale = 0.10206207261596575f;

  const bf16* Qbh = Qp + (size_t)bh * NTOK * HD;
  const bf16* Kbh = Kp + (size_t)bh * NKEY * HD;
  const bf16* Vbh = Vp + (size_t)bh * NKEY * HD;

  for (int idx = tid; idx < 768; idx += 256) {
    int ql = idx / 12, ch = idx % 12;
    int qg = qbase + ql; if (qg > NTOK - 1) qg = NTOK - 1;
    uint4 u = *(const uint4*)(Qbh + (size_t)qg * HD + ch * 8);
    *(uint4*)&Qs[ql * 96 + ch * 8] = u;
  }
  __syncthreads();

  s16x8 qf[3];
  {
    const short* qrow = &Qs[(wid * 16 + kl) * 96];
#pragma unroll
    for (int f = 0; f < 3; f++) qf[f] = *(const s16x8*)(qrow + f * 32 + g * 8);
  }

  for (int idx = tid; idx < 1792; idx += 256) {
    int ql = idx / 28, j = idx % 28;
    int qg = qbase + ql; if (qg > NTOK - 1) qg = NTOK - 1;
    int qy, qx;
    if (qg < 1) { qy = 0; qx = 0; } else { qy = (qg - 1) / 56; qx = (qg - 1) % 56; }
    int ih = qy - 2 * j + 54; ih = ih < 0 ? 0 : (ih > 110 ? 110 : ih);
    int iw = qx - 2 * j + 54; iw = iw < 0 ? 0 : (iw > 110 ? 110 : iw);
    const float* ph = relHt + (size_t)ih * HD;
    const float* pw = relWt + (size_t)iw * HD;
    float dh = 0.f, dw = 0.f;
    for (int c = 0; c < HD; c++) {
      float qv = s2f(Qs[ql * 96 + c]);
      dh += qv * ph[c]; dw += qv * pw[c];
    }
    RH[ql * 28 + j] = f2bs(dh);
    RW[ql * 28 + j] = f2bs(dw);
  }

  auto stage_kv = [&](int t, int buf) {
    for (int idx = tid; idx < 384; idx += 256) {
      int kk = idx / 12, ch = idx % 12;
      int ks = t * 32 + kk; if (ks > 784) ks = 784;
      uint4 u = *(const uint4*)(Kbh + (size_t)ks * HD + ch * 8);
      *(uint4*)&Ks[buf][kk * 128 + ((ch ^ (kk & 7)) << 3)] = u;
      uint4 v = *(const uint4*)(Vbh + (size_t)ks * HD + ch * 8);
      *(uint4*)&Vs[buf][(ch >> 1) * 512 + kk * 16 + ((ch & 1) << 3)] = v;
    }
  };

  stage_kv(0, 0);
  __syncthreads();

  f32x4 o[6];
#pragma unroll
  for (int cb = 0; cb < 6; cb++) o[cb] = (f32x4){0.f, 0.f, 0.f, 0.f};
  float mrow[4] = {-1e30f, -1e30f, -1e30f, -1e30f};
  float lrow[4] = {0.f, 0.f, 0.f, 0.f};

  for (int t = 0; t < 25; t++) {
    const int buf = t & 1;
    if (t < 24) stage_kv(t + 1, buf ^ 1);

    f32x4 s0 = (f32x4){0.f, 0.f, 0.f, 0.f};
    f32x4 s1 = (f32x4){0.f, 0.f, 0.f, 0.f};
#pragma unroll
    for (int f = 0; f < 3; f++) {
      int ch = f * 4 + g;
      int r0 = kl, r1 = 16 + kl;
      s16x8 kf0 = *(const s16x8*)&Ks[buf][r0 * 128 + ((ch ^ (r0 & 7)) << 3)];
      s16x8 kf1 = *(const s16x8*)&Ks[buf][r1 * 128 + ((ch ^ (r1 & 7)) << 3)];
      s0 = __builtin_amdgcn_mfma_f32_16x16x32_bf16(qf[f], kf0, s0, 0, 0, 0);
      s1 = __builtin_amdgcn_mfma_f32_16x16x32_bf16(qf[f], kf1, s1, 0, 0, 0);
    }

    const int k0g = t * 32 + kl;
    const int k1g = k0g + 16;
    int ky0 = (k0g - 1) / 28, kx0 = (k0g - 1) % 28;
    if (kx0 < 0) kx0 = 0;
    int ky1 = (k1g - 1) / 28, kx1 = (k1g - 1) % 28;
    if (ky1 > 27) ky1 = 27;
    float lg0[4], lg1[4];
#pragma unroll
    for (int r = 0; r < 4; r++) {
      int ql = wid * 16 + g * 4 + r;
      int qg = qbase + ql;
      float rel0 = (qg > 0 && k0g > 0) ? s2f(RH[ql * 28 + ky0]) + s2f(RW[ql * 28 + kx0]) : 0.f;
      float rel1 = (qg > 0) ? s2f(RH[ql * 28 + ky1]) + s2f(RW[ql * 28 + kx1]) : 0.f;
      lg0[r] = s0[r] * scale + rel0;
      lg1[r] = (k1g < NKEY) ? (s1[r] * scale + rel1) : -1e30f;
    }

    float tm[4], al[4], p0[4], p1[4], rs[4];
#pragma unroll
    for (int r = 0; r < 4; r++) tm[r] = fmaxf(lg0[r], lg1[r]);
#pragma unroll
    for (int off = 1; off < 16; off <<= 1)
#pragma unroll
      for (int r = 0; r < 4; r++) tm[r] = fmaxf(tm[r], __shfl_xor(tm[r], off));
#pragma unroll
    for (int r = 0; r < 4; r++) {
      float mn = fmaxf(mrow[r], tm[r]);
      al[r] = __expf(mrow[r] - mn);
      p0[r] = __expf(lg0[r] - mn);
      p1[r] = __expf(lg1[r] - mn);
      mrow[r] = mn;
      rs[r] = p0[r] + p1[r];
    }
#pragma unroll
    for (int off = 1; off < 16; off <<= 1)
#pragma unroll
      for (int r = 0; r < 4; r++) rs[r] += __shfl_xor(rs[r], off);
#pragma unroll
    for (int r = 0; r < 4; r++) lrow[r] = lrow[r] * al[r] + rs[r];
#pragma unroll
    for (int cb = 0; cb < 6; cb++)
#pragma unroll
      for (int r = 0; r < 4; r++) o[cb][r] *= al[r];

    short* pw = &Ps[wid][0];
#pragma unroll
    for (int r = 0; r < 4; r++) {
      int q = g * 4 + r;
      int sw = (q >> 1) & 3;
      pw[q * 32 + (((kl >> 3) ^ sw) << 3) + (kl & 7)] = f2bs(p0[r]);
      int k1 = 16 + kl;
      pw[q * 32 + (((k1 >> 3) ^ sw) << 3) + (kl & 7)] = f2bs(p1[r]);
    }
    s16x8 pa = *(const s16x8*)(pw + kl * 32 + ((g ^ ((kl >> 1) & 3)) << 3));

    uint32_t vbase = (uint32_t)(size_t)&Vs[buf][0] + (uint32_t)(g * 256 + kl * 8);
    s16x4 tv[12];
#pragma unroll
    for (int cb = 0; cb < 6; cb++) {
      uint32_t va = vbase + cb * 1024;
      asm volatile("ds_read_b64_tr_b16 %0, %1" : "=v"(tv[2 * cb]) : "v"(va));
      asm volatile("ds_read_b64_tr_b16 %0, %1 offset:128" : "=v"(tv[2 * cb + 1]) : "v"(va));
    }
    asm volatile("s_waitcnt lgkmcnt(0)" ::: "memory");
    __builtin_amdgcn_sched_barrier(0);
#pragma unroll
    for (int cb = 0; cb < 6; cb++) {
      s16x8 vf = __builtin_shufflevector(tv[2 * cb], tv[2 * cb + 1], 0, 1, 2, 3, 4, 5, 6, 7);
      o[cb] = __builtin_amdgcn_mfma_f32_16x16x32_bf16(pa, vf, o[cb], 0, 0, 0);
    }
    __syncthreads();
  }

  float inv[4];
#pragma unroll
  for (int r = 0; r < 4; r++) inv[r] = 1.f / lrow[r];
#pragma unroll
  for (int cb = 0; cb < 6; cb++) {
#pragma unroll
    for (int r = 0; r < 4; r++) {
      int ql = wid * 16 + g * 4 + r;
      int qg = qbase + ql;
      if (qg < NTOK) {
        int c = cb * 16 + kl;
        float val = o[cb][r] * inv[r] + s2f(Qs[ql * 96 + c]);
        out[((size_t)bb * NTOK + qg) * 768 + hh * 96 + c] = val;
      }
    }
  }
}

// ---------------- launch ----------------
extern "C" void kernel_launch(void* const* d_in, const int* in_sizes, int n_in,
                              void* d_out, int out_size, void* d_ws, size_t ws_size,
                              hipStream_t stream) {
  const float* x = (const float*)d_in[0];
  const float* qkv_w = (const float*)d_in[1];
  const float* qkv_b = (const float*)d_in[2];
  const float* pqw = (const float*)d_in[3];
  const float* pkw = (const float*)d_in[4];
  const float* pvw = (const float*)d_in[5];
  const float* nqg = (const float*)d_in[6];
  const float* nqb = (const float*)d_in[7];
  const float* nkg = (const float*)d_in[8];
  const float* nkb = (const float*)d_in[9];
  const float* nvg = (const float*)d_in[10];
  const float* nvb = (const float*)d_in[11];
  const float* relH = (const float*)d_in[12];
  const float* relW = (const float*)d_in[13];

  const size_t SZQ = (size_t)MROWS * DIMC;             // 19,273,728 elems
  const size_t SZK = (size_t)BATCH * NH * NKEY * HD;   //  4,823,040 elems

  // d_out (fp32, 2*SZQ bytes*2): [Xb bf16 SZQ][rawV bf16 SZQ] then final fp32 out.
  // ws (bf16): rawQ [0,SZQ) ; rawK/poolQ [SZQ,2SZQ) ;
  //            WbT->poolK [2SZQ,2SZQ+SZK) ; poolV [+SZK). Peak 96.4 MB.
  bf16* ws = (bf16*)d_ws;
  bf16* Xb   = (bf16*)d_out;
  bf16* rawV = (bf16*)d_out + SZQ;
  bf16* rawQ = ws;
  bf16* rawK = ws + SZQ;
  bf16* WbT  = ws + 2 * SZQ;     // dead before poolK overwrites it
  bf16* poolK = ws + 2 * SZQ;
  bf16* poolV = poolK + SZK;
  bf16* poolQ = rawK;            // aliases rawK (dead after poolK kernel)
  float* out = (float*)d_out;

  k_cvtX<<<2048, 256, 0, stream>>>(x, Xb, (int)(SZQ / 4));
  k_cvtW<<<dim3(DIM3 / 64, DIMC / 64), 256, 0, stream>>>(qkv_w, WbT);

  dim3 g1(DIM3 / 128, (MROWS + 127) / 128);   // (18, 197)
  k_qkv_mfma<<<g1, 256, 0, stream>>>(Xb, WbT, qkv_b, rawQ, rawK, rawV);

  k_pool<2, 28, 28><<<BATCH * NH * NKEY, 64, 0, stream>>>(rawK, pkw, nkg, nkb, poolK);
  k_pool<2, 28, 28><<<BATCH * NH * NKEY, 64, 0, stream>>>(rawV, pvw, nvg, nvb, poolV);
  k_pool<1, 56, 56><<<BATCH * NH * NTOK, 64, 0, stream>>>(rawQ, pqw, nqg, nqb, poolQ);

  k_attn<<<64 * 50, 256, 0, stream>>>(poolQ, poolK, poolV, relH, relW, out);
}